// Round 16
// baseline (240.616 us; speedup 1.0000x reference)
//
#include <hip/hip_runtime.h>

#define DEVI __device__ __forceinline__

typedef __attribute__((ext_vector_type(8))) short short8;
typedef __attribute__((ext_vector_type(4))) float f32x4;

DEVI unsigned short f2bf(float f) {
  unsigned int u = __float_as_uint(f);
  u += 0x7fffu + ((u >> 16) & 1u);
  return (unsigned short)(u >> 16);
}

DEVI void gload16(const void* g, void* l) {
  __builtin_amdgcn_global_load_lds((__attribute__((address_space(1))) void*)g,
                                   (__attribute__((address_space(3))) void*)l, 16, 0, 0);
}

// ---------------- LayerNorm (blocks < 12288) + weight transpose (blocks >= 12288) ----------------
__global__ __launch_bounds__(256) void ln_kernel(
    const float* __restrict__ x, const float* __restrict__ gamma,
    const float* __restrict__ beta, unsigned short* __restrict__ xn,
    const float* __restrict__ Wq, const float* __restrict__ Wp,
    unsigned short* __restrict__ Wtq, unsigned short* __restrict__ Wtp) {
  int tid = threadIdx.x;
  if (blockIdx.x >= 12288) {
    int idx = (blockIdx.x - 12288) * 256 + tid;
    const int stride = 512 * 256;
    for (int i = idx; i < 1536 * 512; i += stride) {
      int n = i >> 9, k = i & 511;
      Wtq[i] = f2bf(Wq[(size_t)k * 1536 + n]);
    }
    for (int i = idx; i < 512 * 512; i += stride) {
      int n = i >> 9, k = i & 511;
      Wtp[i] = f2bf(Wp[(size_t)k * 512 + n]);
    }
    return;
  }
  int w = tid >> 6, l = tid & 63;
  size_t row = (size_t)blockIdx.x * 4 + w;
  const float* xr = x + row * 512 + l * 8;
  float4 v0 = *(const float4*)xr;
  float4 v1 = *(const float4*)(xr + 4);
  float s  = v0.x + v0.y + v0.z + v0.w + v1.x + v1.y + v1.z + v1.w;
  float ss = v0.x*v0.x + v0.y*v0.y + v0.z*v0.z + v0.w*v0.w
           + v1.x*v1.x + v1.y*v1.y + v1.z*v1.z + v1.w*v1.w;
  #pragma unroll
  for (int m = 1; m < 64; m <<= 1) {
    s  += __shfl_xor(s,  m);
    ss += __shfl_xor(ss, m);
  }
  float mean = s * (1.f / 512.f);
  float var  = ss * (1.f / 512.f) - mean * mean;
  float rstd = rsqrtf(var + 1e-5f);
  float4 g0 = *(const float4*)(gamma + l * 8);
  float4 g1 = *(const float4*)(gamma + l * 8 + 4);
  float4 b0 = *(const float4*)(beta + l * 8);
  float4 b1 = *(const float4*)(beta + l * 8 + 4);
  short8 ov;
  ov[0] = (short)f2bf((v0.x - mean) * rstd * g0.x + b0.x);
  ov[1] = (short)f2bf((v0.y - mean) * rstd * g0.y + b0.y);
  ov[2] = (short)f2bf((v0.z - mean) * rstd * g0.z + b0.z);
  ov[3] = (short)f2bf((v0.w - mean) * rstd * g0.w + b0.w);
  ov[4] = (short)f2bf((v1.x - mean) * rstd * g1.x + b1.x);
  ov[5] = (short)f2bf((v1.y - mean) * rstd * g1.y + b1.y);
  ov[6] = (short)f2bf((v1.z - mean) * rstd * g1.z + b1.z);
  ov[7] = (short)f2bf((v1.w - mean) * rstd * g1.w + b1.w);
  *(short8*)(xn + row * 512 + l * 8) = ov;
}

// ---------------- 256x256 deep-pipelined GEMM (counted vmcnt, raw barriers) ----------------
// C[M][N] = A[M][K] * Bt[N][K]^T, bf16 out. 512 thr = 8 waves (2Mx4N), per-wave 128x64.
// LDS 128 KB: buf b at b*65536: A-tile [256][64] @0, B-tile @32768, both T2-swizzled
// (linear dest via gload16 + pre-swizzled source col; read XOR ((row&7)<<4)).
// Pipeline: stage t+1 -> vmcnt(8) (t resident, t+1 in flight ACROSS the barrier) ->
// s_barrier -> 64 MFMA -> s_barrier. Ledger: buffer b[(t+1)&1] overwritten only after
// all waves crossed iter-(t-1)'s trailing barrier (reads done).
__global__ __launch_bounds__(512, 1) void gemm256(
    const unsigned short* __restrict__ A, const unsigned short* __restrict__ Bt,
    unsigned short* __restrict__ Cbf, int M, int N, int K, int nbx) {
  __shared__ __align__(16) char smem[131072];
  int tid = threadIdx.x;
  int wid = tid >> 6, l = tid & 63;
  int lr = l & 15, g = l >> 4;
  int wr = wid >> 2, wc = wid & 3;
  int nwg = nbx * gridDim.y;
  int lin = blockIdx.y * nbx + blockIdx.x;
  int cpx = nwg >> 3;
  int swz = (lin & 7) * cpx + (lin >> 3);
  int bn = swz % nbx, bm = swz / nbx;
  const unsigned short* Ab = A + (size_t)bm * 256 * K;
  const unsigned short* Bb = Bt + (size_t)bn * 256 * K;
  int t8 = tid >> 3;                         // row within 64-row staging chunk
  int c8s = (((tid & 7) ^ (t8 & 7)) * 8);    // pre-swizzled source col

  f32x4 zero = {0.f, 0.f, 0.f, 0.f};
  f32x4 acc[8][4];
  #pragma unroll
  for (int mi = 0; mi < 8; mi++)
    #pragma unroll
    for (int nj = 0; nj < 4; nj++) acc[mi][nj] = zero;

  // prologue: stage K-tile 0 into buf0
  #pragma unroll
  for (int c = 0; c < 4; c++) {
    gload16(Ab + (size_t)(c * 64 + t8) * K + c8s, smem + c * 8192 + wid * 1024);
    gload16(Bb + (size_t)(c * 64 + t8) * K + c8s, smem + 32768 + c * 8192 + wid * 1024);
  }

  for (int t = 0; t < 8; ++t) {
    if (t < 7) {
      char* dst = smem + ((t + 1) & 1) * 65536;
      int k0 = (t + 1) * 64;
      #pragma unroll
      for (int c = 0; c < 4; c++) {
        gload16(Ab + (size_t)(c * 64 + t8) * K + k0 + c8s, dst + c * 8192 + wid * 1024);
        gload16(Bb + (size_t)(c * 64 + t8) * K + k0 + c8s, dst + 32768 + c * 8192 + wid * 1024);
      }
      asm volatile("s_waitcnt vmcnt(8)" ::: "memory");
    } else {
      asm volatile("s_waitcnt vmcnt(0)" ::: "memory");
    }
    __builtin_amdgcn_s_barrier();
    __builtin_amdgcn_sched_barrier(0);
    const char* Al = smem + (t & 1) * 65536;
    const char* Bl = Al + 32768;
    #pragma unroll
    for (int ks = 0; ks < 2; ks++) {
      short8 a[8], b[4];
      #pragma unroll
      for (int mi = 0; mi < 8; mi++) {
        int ra = wr * 128 + mi * 16 + lr;
        a[mi] = *(const short8*)(Al + ra * 128 + ((ks * 64 + g * 16) ^ ((ra & 7) << 4)));
      }
      #pragma unroll
      for (int nj = 0; nj < 4; nj++) {
        int rb = wc * 64 + nj * 16 + lr;
        b[nj] = *(const short8*)(Bl + rb * 128 + ((ks * 64 + g * 16) ^ ((rb & 7) << 4)));
      }
      __builtin_amdgcn_s_setprio(1);
      #pragma unroll
      for (int mi = 0; mi < 8; mi++)
        #pragma unroll
        for (int nj = 0; nj < 4; nj++)
          acc[mi][nj] = __builtin_amdgcn_mfma_f32_16x16x32_bf16(a[mi], b[nj], acc[mi][nj], 0, 0, 0);
      __builtin_amdgcn_s_setprio(0);
    }
    __builtin_amdgcn_sched_barrier(0);
    __builtin_amdgcn_s_barrier();
  }

  int rb0 = bm * 256 + wr * 128 + g * 4;
  int cb0 = bn * 256 + wc * 64 + lr;
  #pragma unroll
  for (int mi = 0; mi < 8; mi++)
    #pragma unroll
    for (int nj = 0; nj < 4; nj++)
      #pragma unroll
      for (int r = 0; r < 4; r++)
        Cbf[(size_t)(rb0 + mi * 16 + r) * N + cb0 + nj * 16] = f2bf(acc[mi][nj][r]);
}

// ---------------- GEMM: C[M][N] = A[M][K] * Bt[N][K]^T (r15 verbatim; used for proj) ----------------
template<int EPI>
__global__ __launch_bounds__(256, 2) void gemm_bt(
    const unsigned short* __restrict__ A, const unsigned short* __restrict__ Bt,
    unsigned short* __restrict__ Cbf, float* __restrict__ Cf,
    const float* __restrict__ bias, const float* __restrict__ resid,
    int M, int N, int K, int nbx) {
  __shared__ __align__(16) char gsmem[32768];
  unsigned short* As = (unsigned short*)gsmem;
  unsigned short* Bs = As + 128 * 64;
  float* Cs = (float*)gsmem;
  int tid = threadIdx.x;
  int w = tid >> 6, l = tid & 63;
  int nwg = nbx * gridDim.y;
  int lin = blockIdx.y * nbx + blockIdx.x;
  int cpx = nwg >> 3;
  int swz = (lin & 7) * cpx + (lin >> 3);
  int bn = swz % nbx, bm = swz / nbx;
  int wr = w >> 1, wc = w & 1;
  int t8 = tid >> 3;
  int c8s = (((tid & 7) ^ ((tid >> 3) & 7)) * 8);
  int lr = l & 15, lk4 = l >> 4;
  const unsigned short* Ab = A + (size_t)bm * 128 * K;
  const unsigned short* Bb = Bt + (size_t)bn * 128 * K;
  f32x4 zero = {0.f, 0.f, 0.f, 0.f};
  f32x4 acc[4][4];
  #pragma unroll
  for (int i = 0; i < 4; i++)
    #pragma unroll
    for (int j = 0; j < 4; j++) acc[i][j] = zero;

  for (int k0 = 0; k0 < K; k0 += 64) {
    #pragma unroll
    for (int i = 0; i < 4; i++) {
      gload16(Ab + (size_t)(i * 32 + t8) * K + k0 + c8s, (char*)As + i * 4096 + w * 1024);
      gload16(Bb + (size_t)(i * 32 + t8) * K + k0 + c8s, (char*)Bs + i * 4096 + w * 1024);
    }
    __syncthreads();
    #pragma unroll
    for (int kk = 0; kk < 2; kk++) {
      short8 a[4], b[4];
      #pragma unroll
      for (int i = 0; i < 4; i++) {
        int ra = wr * 64 + i * 16 + lr;
        a[i] = *(const short8*)((const char*)As + ra * 128 +
                                (((kk * 64 + lk4 * 16)) ^ ((ra & 7) << 4)));
      }
      #pragma unroll
      for (int j = 0; j < 4; j++) {
        int rb = wc * 64 + j * 16 + lr;
        b[j] = *(const short8*)((const char*)Bs + rb * 128 +
                                (((kk * 64 + lk4 * 16)) ^ ((rb & 7) << 4)));
      }
      #pragma unroll
      for (int i = 0; i < 4; i++)
        #pragma unroll
        for (int j = 0; j < 4; j++)
          acc[i][j] = __builtin_amdgcn_mfma_f32_16x16x32_bf16(a[i], b[j], acc[i][j], 0, 0, 0);
    }
    __syncthreads();
  }
  if (EPI == 0) {
    int rb = bm * 128 + wr * 64 + lk4 * 4;
    int cb = bn * 128 + wc * 64 + lr;
    #pragma unroll
    for (int i = 0; i < 4; i++)
      #pragma unroll
      for (int j = 0; j < 4; j++)
        #pragma unroll
        for (int r = 0; r < 4; r++)
          Cbf[(size_t)(rb + i * 16 + r) * N + (cb + j * 16)] = f2bf(acc[i][j][r]);
  } else {
    #pragma unroll
    for (int c = 0; c < 2; c++) {
      if (wr == c) {
        #pragma unroll
        for (int i = 0; i < 4; i++)
          #pragma unroll
          for (int j = 0; j < 4; j++)
            #pragma unroll
            for (int r = 0; r < 4; r++)
              Cs[(i * 16 + lk4 * 4 + r) * 128 + wc * 64 + j * 16 + lr] = acc[i][j][r];
      }
      __syncthreads();
      #pragma unroll
      for (int it = 0; it < 8; it++) {
        int lrow = it * 8 + (tid >> 5);
        int col = (tid & 31) * 4;
        float4 v = *(const float4*)&Cs[lrow * 128 + col];
        int grow = bm * 128 + c * 64 + lrow;
        int gcol = bn * 128 + col;
        float4 bi = *(const float4*)(bias + gcol);
        float4 rs = *(const float4*)(resid + (size_t)grow * N + gcol);
        v.x += bi.x + rs.x;
        v.y += bi.y + rs.y;
        v.z += bi.z + rs.z;
        v.w += bi.w + rs.w;
        *(float4*)(Cf + (size_t)grow * N + gcol) = v;
      }
      __syncthreads();
    }
  }
}

// ---------------- fused masked attention (r15 verbatim) ----------------
__global__ __launch_bounds__(256, 2) void attn_kernel(
    const unsigned short* __restrict__ qkv, unsigned short* __restrict__ aout,
    const int* __restrict__ obs_mask, const int* __restrict__ pad_mask) {
  __shared__ __align__(16) char smem[52480];
  char* KsB = smem;
  unsigned short* Vt = (unsigned short*)smem;      // aliases KsB after sync#2
  char* Pw = smem + 25600;
  float* obsb = (float*)(smem + 50176);
  int*   padb = (int*)(smem + 50944);
  float* kbT  = (float*)(smem + 51712);

  const float LOG2E = 1.44269504f;
  const float K2 = 0.18033688f;        // 0.125 * log2(e)
  const float C2 = -1.44269504e9f;     // -1e9 * log2(e), exactly -1442695040.0f

  int h = blockIdx.x, bv = blockIdx.y;
  int tid = threadIdx.x, w = tid >> 6, l = tid & 63;
  int lr = l & 15, lk4 = l >> 4;
  int b = bv >> 5;
  for (int t = tid; t < 192; t += 256) {
    float obs = (t == 0) ? 1.f : (float)obs_mask[bv * 191 + (t - 1)];
    int pad = (t == 0) ? 1 : pad_mask[b * 191 + (t - 1)];
    obsb[t] = obs;
    padb[t] = pad;
    kbT[t] = obs * LOG2E + (pad ? 0.f : C2);
  }
  const unsigned short* base = qkv + (size_t)bv * 192 * 1536 + h * 64;

  #pragma unroll
  for (int it = 0; it < 6; it++) {
    int s = it * 256 + tid;
    int row = s >> 3, slot = s & 7;
    gload16(base + (size_t)row * 1536 + 512 + (slot ^ (row & 7)) * 8,
            KsB + it * 4096 + w * 1024);
  }
  short8 qf[3][2];
  #pragma unroll
  for (int i = 0; i < 3; i++)
    #pragma unroll
    for (int kk = 0; kk < 2; kk++)
      qf[i][kk] = *(const short8*)(base + (size_t)(w * 48 + i * 16 + lr) * 1536 + kk * 32 + lk4 * 8);

  __syncthreads();
  f32x4 zero = {0.f, 0.f, 0.f, 0.f};
  f32x4 sc[3][12];
  #pragma unroll
  for (int i = 0; i < 3; i++)
    #pragma unroll
    for (int j = 0; j < 12; j++) sc[i][j] = zero;
  #pragma unroll
  for (int kk = 0; kk < 2; kk++) {
    short8 bb[12];
    #pragma unroll
    for (int j = 0; j < 12; j++) {
      int row = j * 16 + lr;
      bb[j] = *(const short8*)(KsB + row * 128 + ((kk * 64 + lk4 * 16) ^ ((row & 7) << 4)));
    }
    __builtin_amdgcn_s_setprio(1);
    #pragma unroll
    for (int i = 0; i < 3; i++)
      #pragma unroll
      for (int j = 0; j < 12; j++)
        sc[i][j] = __builtin_amdgcn_mfma_f32_16x16x32_bf16(qf[i][kk], bb[j], sc[i][j], 0, 0, 0);
    __builtin_amdgcn_s_setprio(0);
  }
  __syncthreads();  // all waves done reading KsB

  #pragma unroll
  for (int it = 0; it < 3; it++) {
    int s = it * 256 + tid;
    int kp = s >> 3;
    int d0 = (s & 7) * 8;
    short8 va = *(const short8*)(base + (size_t)(kp * 2) * 1536 + 1024 + d0);
    short8 vb = *(const short8*)(base + (size_t)(kp * 2 + 1) * 1536 + 1024 + d0);
    int slot = ((d0 >> 3) & 7) << 4;
    #pragma unroll
    for (int e = 0; e < 8; e++) {
      int byte = (((d0 + e) * 400 + kp * 4) ^ slot);
      *(unsigned int*)((char*)Vt + byte) =
          ((unsigned int)(unsigned short)vb[e] << 16) | (unsigned int)(unsigned short)va[e];
    }
  }

  float cT[12];
  #pragma unroll
  for (int j = 0; j < 12; j++) cT[j] = kbT[j * 16 + lr];
  unsigned int pf[3][2][12];
  #pragma unroll
  for (int i = 0; i < 3; i++) {
    #pragma unroll
    for (int r = 0; r < 4; r++) {
      int row = w * 48 + i * 16 + lk4 * 4 + r;
      float ro2 = obsb[row] * LOG2E;
      int rp = padb[row];
      float sum = 0.f;
      #pragma unroll
      for (int j = 0; j < 12; j++) {
        float vv = fmaf(sc[i][j][r], K2, ro2 + cT[j]);
        float e = rp ? __builtin_amdgcn_exp2f(vv) : 1.0f;
        sc[i][j][r] = e;
        sum += e;
      }
      #pragma unroll
      for (int m = 1; m < 16; m <<= 1) sum += __shfl_xor(sum, m);
      float inv = 1.f / sum;
      #pragma unroll
      for (int j = 0; j < 12; j++) sc[i][j][r] *= inv;
    }
    #pragma unroll
    for (int j = 0; j < 12; j++) {
      asm("v_cvt_pk_bf16_f32 %0, %1, %2"
          : "=v"(pf[i][0][j]) : "v"(sc[i][j][0]), "v"(sc[i][j][1]));
      asm("v_cvt_pk_bf16_f32 %0, %1, %2"
          : "=v"(pf[i][1][j]) : "v"(sc[i][j][2]), "v"(sc[i][j][3]));
    }
  }
  __syncthreads();  // Vt staged & visible to all waves

  char* Pme = Pw + w * 6144;
  f32x4 o[3][4];
  #pragma unroll
  for (int i = 0; i < 3; i++)
    #pragma unroll
    for (int jd = 0; jd < 4; jd++) o[i][jd] = zero;
  #pragma unroll
  for (int kc = 0; kc < 3; kc++) {
    #pragma unroll
    for (int i = 0; i < 3; i++)
      #pragma unroll
      for (int rp = 0; rp < 2; rp++) {
        int row0 = i * 16 + lk4 * 4 + rp * 2;
        int row1 = row0 + 1;
        #pragma unroll
        for (int jj = 0; jj < 4; jj++) {
          unsigned int v = pf[i][rp][kc * 4 + jj];
          int c2 = (jj * 16 + lr) * 2;
          *(unsigned short*)(Pme + row0 * 128 + (c2 ^ ((row0 & 7) << 4))) = (unsigned short)v;
          *(unsigned short*)(Pme + row1 * 128 + (c2 ^ ((row1 & 7) << 4))) = (unsigned short)(v >> 16);
        }
      }
    asm volatile("s_waitcnt lgkmcnt(0)" ::: "memory");
    __builtin_amdgcn_sched_barrier(0);
    #pragma unroll
    for (int kk = 0; kk < 2; kk++) {
      short8 a[3], bb[4];
      #pragma unroll
      for (int i = 0; i < 3; i++) {
        int ra = i * 16 + lr;
        a[i] = *(const short8*)(Pme + ra * 128 + (((kk * 32 + lk4 * 8) * 2) ^ ((ra & 7) << 4)));
      }
      #pragma unroll
      for (int jd = 0; jd < 4; jd++) {
        int d = jd * 16 + lr;
        int byte = ((d * 400 + (kc * 64 + kk * 32 + lk4 * 8) * 2) ^ (((d >> 3) & 7) << 4));
        bb[jd] = *(const short8*)((const char*)Vt + byte);
      }
      __builtin_amdgcn_s_setprio(1);
      #pragma unroll
      for (int i = 0; i < 3; i++)
        #pragma unroll
        for (int jd = 0; jd < 4; jd++)
          o[i][jd] = __builtin_amdgcn_mfma_f32_16x16x32_bf16(a[i], bb[jd], o[i][jd], 0, 0, 0);
      __builtin_amdgcn_s_setprio(0);
    }
  }

  asm volatile("s_waitcnt lgkmcnt(0)" ::: "memory");
  __builtin_amdgcn_sched_barrier(0);
  #pragma unroll
  for (int i = 0; i < 3; i++)
    #pragma unroll
    for (int jd = 0; jd < 4; jd++)
      #pragma unroll
      for (int h2 = 0; h2 < 2; h2++) {
        unsigned int u;
        asm("v_cvt_pk_bf16_f32 %0, %1, %2"
            : "=v"(u) : "v"(o[i][jd][h2 * 2]), "v"(o[i][jd][h2 * 2 + 1]));
        int row0 = i * 16 + lk4 * 4 + h2 * 2;
        int row1 = row0 + 1;
        int c2 = (jd * 16 + lr) * 2;
        *(unsigned short*)(Pme + row0 * 128 + (c2 ^ ((row0 & 7) << 4))) = (unsigned short)u;
        *(unsigned short*)(Pme + row1 * 128 + (c2 ^ ((row1 & 7) << 4))) = (unsigned short)(u >> 16);
      }
  asm volatile("s_waitcnt lgkmcnt(0)" ::: "memory");
  __builtin_amdgcn_sched_barrier(0);
  unsigned short* ob2 = aout + (size_t)(bv * 192 + w * 48) * 512 + h * 64;
  #pragma unroll
  for (int p = 0; p < 6; p++) {
    int row = p * 8 + (l >> 3);
    int c = l & 7;
    int slot = (row & 7) << 4;
    short8 v = *(const short8*)(Pme + row * 128 + ((c * 16) ^ slot));
    *(short8*)(ob2 + (size_t)row * 512 + c * 8) = v;
  }
}

extern "C" void kernel_launch(void* const* d_in, const int* in_sizes, int n_in,
                              void* d_out, int out_size, void* d_ws, size_t ws_size,
                              hipStream_t stream) {
  const float* x     = (const float*)d_in[0];
  const int*   obs   = (const int*)d_in[1];
  const int*   pad   = (const int*)d_in[2];
  const float* gamma = (const float*)d_in[3];
  const float* beta  = (const float*)d_in[4];
  const float* Wq    = (const float*)d_in[5];
  const float* Wp    = (const float*)d_in[6];
  const float* bp    = (const float*)d_in[7];
  float* out = (float*)d_out;
  char* ws = (char*)d_ws;

  const size_t M = 49152;  // BV * T1 = 256 * 192
  unsigned short* xn  = (unsigned short*)ws;                             // M*512 bf16 (reused as attn out)
  unsigned short* qkv = (unsigned short*)(ws + M * 512 * 2);             // M*1536 bf16
  unsigned short* Wtq = (unsigned short*)(ws + M * 512 * 2 + M * 1536 * 2);
  unsigned short* Wtp = Wtq + 1536 * 512;

  ln_kernel<<<dim3(12800), dim3(256), 0, stream>>>(x, gamma, beta, xn, Wq, Wp, Wtq, Wtp);
  gemm256<<<dim3(6, 192), dim3(512), 0, stream>>>(xn, Wtq, qkv, 49152, 1536, 512, 6);
  attn_kernel<<<dim3(8, 256), dim3(256), 0, stream>>>(qkv, xn, obs, pad);
  gemm_bt<1><<<dim3(4, 384), dim3(256), 0, stream>>>(
      xn, Wtp, nullptr, out, bp, x, 49152, 512, 512, 4);
}

// Round 17
// 228.753 us; speedup vs baseline: 1.0519x; 1.0519x over previous
//
#include <hip/hip_runtime.h>

#define DEVI __device__ __forceinline__

typedef __attribute__((ext_vector_type(8))) short short8;
typedef __attribute__((ext_vector_type(4))) float f32x4;

DEVI unsigned short f2bf(float f) {
  unsigned int u = __float_as_uint(f);
  u += 0x7fffu + ((u >> 16) & 1u);
  return (unsigned short)(u >> 16);
}

DEVI void gload16(const void* g, void* l) {
  __builtin_amdgcn_global_load_lds((__attribute__((address_space(1))) void*)g,
                                   (__attribute__((address_space(3))) void*)l, 16, 0, 0);
}

// ---------------- LayerNorm (blocks < 12288) + weight transpose (blocks >= 12288) ----------------
__global__ __launch_bounds__(256) void ln_kernel(
    const float* __restrict__ x, const float* __restrict__ gamma,
    const float* __restrict__ beta, unsigned short* __restrict__ xn,
    const float* __restrict__ Wq, const float* __restrict__ Wp,
    unsigned short* __restrict__ Wtq, unsigned short* __restrict__ Wtp) {
  int tid = threadIdx.x;
  if (blockIdx.x >= 12288) {
    int idx = (blockIdx.x - 12288) * 256 + tid;
    const int stride = 512 * 256;
    for (int i = idx; i < 1536 * 512; i += stride) {
      int n = i >> 9, k = i & 511;
      Wtq[i] = f2bf(Wq[(size_t)k * 1536 + n]);
    }
    for (int i = idx; i < 512 * 512; i += stride) {
      int n = i >> 9, k = i & 511;
      Wtp[i] = f2bf(Wp[(size_t)k * 512 + n]);
    }
    return;
  }
  int w = tid >> 6, l = tid & 63;
  size_t row = (size_t)blockIdx.x * 4 + w;
  const float* xr = x + row * 512 + l * 8;
  float4 v0 = *(const float4*)xr;
  float4 v1 = *(const float4*)(xr + 4);
  float s  = v0.x + v0.y + v0.z + v0.w + v1.x + v1.y + v1.z + v1.w;
  float ss = v0.x*v0.x + v0.y*v0.y + v0.z*v0.z + v0.w*v0.w
           + v1.x*v1.x + v1.y*v1.y + v1.z*v1.z + v1.w*v1.w;
  #pragma unroll
  for (int m = 1; m < 64; m <<= 1) {
    s  += __shfl_xor(s,  m);
    ss += __shfl_xor(ss, m);
  }
  float mean = s * (1.f / 512.f);
  float var  = ss * (1.f / 512.f) - mean * mean;
  float rstd = rsqrtf(var + 1e-5f);
  float4 g0 = *(const float4*)(gamma + l * 8);
  float4 g1 = *(const float4*)(gamma + l * 8 + 4);
  float4 b0 = *(const float4*)(beta + l * 8);
  float4 b1 = *(const float4*)(beta + l * 8 + 4);
  short8 ov;
  ov[0] = (short)f2bf((v0.x - mean) * rstd * g0.x + b0.x);
  ov[1] = (short)f2bf((v0.y - mean) * rstd * g0.y + b0.y);
  ov[2] = (short)f2bf((v0.z - mean) * rstd * g0.z + b0.z);
  ov[3] = (short)f2bf((v0.w - mean) * rstd * g0.w + b0.w);
  ov[4] = (short)f2bf((v1.x - mean) * rstd * g1.x + b1.x);
  ov[5] = (short)f2bf((v1.y - mean) * rstd * g1.y + b1.y);
  ov[6] = (short)f2bf((v1.z - mean) * rstd * g1.z + b1.z);
  ov[7] = (short)f2bf((v1.w - mean) * rstd * g1.w + b1.w);
  *(short8*)(xn + row * 512 + l * 8) = ov;
}

// ---------------- GEMM: C[M][N] = A[M][K] * Bt[N][K]^T (T2 swizzle + XCD remap) ----------------
// EPI==0: bf16 out.  EPI==1: fp32 out via LDS-staged coalesced epilogue.
template<int EPI>
__global__ __launch_bounds__(256, 2) void gemm_bt(
    const unsigned short* __restrict__ A, const unsigned short* __restrict__ Bt,
    unsigned short* __restrict__ Cbf, float* __restrict__ Cf,
    const float* __restrict__ bias, const float* __restrict__ resid,
    int M, int N, int K, int nbx) {
  __shared__ __align__(16) char gsmem[32768];
  unsigned short* As = (unsigned short*)gsmem;
  unsigned short* Bs = As + 128 * 64;
  float* Cs = (float*)gsmem;
  int tid = threadIdx.x;
  int w = tid >> 6, l = tid & 63;
  int nwg = nbx * gridDim.y;
  int lin = blockIdx.y * nbx + blockIdx.x;
  int cpx = nwg >> 3;
  int swz = (lin & 7) * cpx + (lin >> 3);
  int bn = swz % nbx, bm = swz / nbx;
  int wr = w >> 1, wc = w & 1;
  int t8 = tid >> 3;
  int c8s = (((tid & 7) ^ ((tid >> 3) & 7)) * 8);
  int lr = l & 15, lk4 = l >> 4;
  const unsigned short* Ab = A + (size_t)bm * 128 * K;
  const unsigned short* Bb = Bt + (size_t)bn * 128 * K;
  f32x4 zero = {0.f, 0.f, 0.f, 0.f};
  f32x4 acc[4][4];
  #pragma unroll
  for (int i = 0; i < 4; i++)
    #pragma unroll
    for (int j = 0; j < 4; j++) acc[i][j] = zero;

  for (int k0 = 0; k0 < K; k0 += 64) {
    #pragma unroll
    for (int i = 0; i < 4; i++) {
      gload16(Ab + (size_t)(i * 32 + t8) * K + k0 + c8s, (char*)As + i * 4096 + w * 1024);
      gload16(Bb + (size_t)(i * 32 + t8) * K + k0 + c8s, (char*)Bs + i * 4096 + w * 1024);
    }
    __syncthreads();
    #pragma unroll
    for (int kk = 0; kk < 2; kk++) {
      short8 a[4], b[4];
      #pragma unroll
      for (int i = 0; i < 4; i++) {
        int ra = wr * 64 + i * 16 + lr;
        a[i] = *(const short8*)((const char*)As + ra * 128 +
                                (((kk * 64 + lk4 * 16)) ^ ((ra & 7) << 4)));
      }
      #pragma unroll
      for (int j = 0; j < 4; j++) {
        int rb = wc * 64 + j * 16 + lr;
        b[j] = *(const short8*)((const char*)Bs + rb * 128 +
                                (((kk * 64 + lk4 * 16)) ^ ((rb & 7) << 4)));
      }
      #pragma unroll
      for (int i = 0; i < 4; i++)
        #pragma unroll
        for (int j = 0; j < 4; j++)
          acc[i][j] = __builtin_amdgcn_mfma_f32_16x16x32_bf16(a[i], b[j], acc[i][j], 0, 0, 0);
    }
    __syncthreads();
  }
  if (EPI == 0) {
    int rb = bm * 128 + wr * 64 + lk4 * 4;
    int cb = bn * 128 + wc * 64 + lr;
    #pragma unroll
    for (int i = 0; i < 4; i++)
      #pragma unroll
      for (int j = 0; j < 4; j++)
        #pragma unroll
        for (int r = 0; r < 4; r++)
          Cbf[(size_t)(rb + i * 16 + r) * N + (cb + j * 16)] = f2bf(acc[i][j][r]);
  } else {
    #pragma unroll
    for (int c = 0; c < 2; c++) {
      if (wr == c) {
        #pragma unroll
        for (int i = 0; i < 4; i++)
          #pragma unroll
          for (int j = 0; j < 4; j++)
            #pragma unroll
            for (int r = 0; r < 4; r++)
              Cs[(i * 16 + lk4 * 4 + r) * 128 + wc * 64 + j * 16 + lr] = acc[i][j][r];
      }
      __syncthreads();
      #pragma unroll
      for (int it = 0; it < 8; it++) {
        int lrow = it * 8 + (tid >> 5);
        int col = (tid & 31) * 4;
        float4 v = *(const float4*)&Cs[lrow * 128 + col];
        int grow = bm * 128 + c * 64 + lrow;
        int gcol = bn * 128 + col;
        float4 bi = *(const float4*)(bias + gcol);
        float4 rs = *(const float4*)(resid + (size_t)grow * N + gcol);
        v.x += bi.x + rs.x;
        v.y += bi.y + rs.y;
        v.z += bi.z + rs.z;
        v.w += bi.w + rs.w;
        *(float4*)(Cf + (size_t)grow * N + gcol) = v;
      }
      __syncthreads();
    }
  }
}

// ---------------- fused masked attention (r15 verbatim) ----------------
__global__ __launch_bounds__(256, 2) void attn_kernel(
    const unsigned short* __restrict__ qkv, unsigned short* __restrict__ aout,
    const int* __restrict__ obs_mask, const int* __restrict__ pad_mask) {
  __shared__ __align__(16) char smem[52480];
  char* KsB = smem;
  unsigned short* Vt = (unsigned short*)smem;      // aliases KsB after sync#2
  char* Pw = smem + 25600;
  float* obsb = (float*)(smem + 50176);
  int*   padb = (int*)(smem + 50944);
  float* kbT  = (float*)(smem + 51712);

  const float LOG2E = 1.44269504f;
  const float K2 = 0.18033688f;        // 0.125 * log2(e)
  const float C2 = -1.44269504e9f;     // -1e9 * log2(e), exactly -1442695040.0f

  int h = blockIdx.x, bv = blockIdx.y;
  int tid = threadIdx.x, w = tid >> 6, l = tid & 63;
  int lr = l & 15, lk4 = l >> 4;
  int b = bv >> 5;
  for (int t = tid; t < 192; t += 256) {
    float obs = (t == 0) ? 1.f : (float)obs_mask[bv * 191 + (t - 1)];
    int pad = (t == 0) ? 1 : pad_mask[b * 191 + (t - 1)];
    obsb[t] = obs;
    padb[t] = pad;
    kbT[t] = obs * LOG2E + (pad ? 0.f : C2);
  }
  const unsigned short* base = qkv + (size_t)bv * 192 * 1536 + h * 64;

  #pragma unroll
  for (int it = 0; it < 6; it++) {
    int s = it * 256 + tid;
    int row = s >> 3, slot = s & 7;
    gload16(base + (size_t)row * 1536 + 512 + (slot ^ (row & 7)) * 8,
            KsB + it * 4096 + w * 1024);
  }
  short8 qf[3][2];
  #pragma unroll
  for (int i = 0; i < 3; i++)
    #pragma unroll
    for (int kk = 0; kk < 2; kk++)
      qf[i][kk] = *(const short8*)(base + (size_t)(w * 48 + i * 16 + lr) * 1536 + kk * 32 + lk4 * 8);

  __syncthreads();
  f32x4 zero = {0.f, 0.f, 0.f, 0.f};
  f32x4 sc[3][12];
  #pragma unroll
  for (int i = 0; i < 3; i++)
    #pragma unroll
    for (int j = 0; j < 12; j++) sc[i][j] = zero;
  #pragma unroll
  for (int kk = 0; kk < 2; kk++) {
    short8 bb[12];
    #pragma unroll
    for (int j = 0; j < 12; j++) {
      int row = j * 16 + lr;
      bb[j] = *(const short8*)(KsB + row * 128 + ((kk * 64 + lk4 * 16) ^ ((row & 7) << 4)));
    }
    __builtin_amdgcn_s_setprio(1);
    #pragma unroll
    for (int i = 0; i < 3; i++)
      #pragma unroll
      for (int j = 0; j < 12; j++)
        sc[i][j] = __builtin_amdgcn_mfma_f32_16x16x32_bf16(qf[i][kk], bb[j], sc[i][j], 0, 0, 0);
    __builtin_amdgcn_s_setprio(0);
  }
  __syncthreads();  // all waves done reading KsB

  #pragma unroll
  for (int it = 0; it < 3; it++) {
    int s = it * 256 + tid;
    int kp = s >> 3;
    int d0 = (s & 7) * 8;
    short8 va = *(const short8*)(base + (size_t)(kp * 2) * 1536 + 1024 + d0);
    short8 vb = *(const short8*)(base + (size_t)(kp * 2 + 1) * 1536 + 1024 + d0);
    int slot = ((d0 >> 3) & 7) << 4;
    #pragma unroll
    for (int e = 0; e < 8; e++) {
      int byte = (((d0 + e) * 400 + kp * 4) ^ slot);
      *(unsigned int*)((char*)Vt + byte) =
          ((unsigned int)(unsigned short)vb[e] << 16) | (unsigned int)(unsigned short)va[e];
    }
  }

  float cT[12];
  #pragma unroll
  for (int j = 0; j < 12; j++) cT[j] = kbT[j * 16 + lr];
  unsigned int pf[3][2][12];
  #pragma unroll
  for (int i = 0; i < 3; i++) {
    #pragma unroll
    for (int r = 0; r < 4; r++) {
      int row = w * 48 + i * 16 + lk4 * 4 + r;
      float ro2 = obsb[row] * LOG2E;
      int rp = padb[row];
      float sum = 0.f;
      #pragma unroll
      for (int j = 0; j < 12; j++) {
        float vv = fmaf(sc[i][j][r], K2, ro2 + cT[j]);
        float e = rp ? __builtin_amdgcn_exp2f(vv) : 1.0f;
        sc[i][j][r] = e;
        sum += e;
      }
      #pragma unroll
      for (int m = 1; m < 16; m <<= 1) sum += __shfl_xor(sum, m);
      float inv = 1.f / sum;
      #pragma unroll
      for (int j = 0; j < 12; j++) sc[i][j][r] *= inv;
    }
    #pragma unroll
    for (int j = 0; j < 12; j++) {
      asm("v_cvt_pk_bf16_f32 %0, %1, %2"
          : "=v"(pf[i][0][j]) : "v"(sc[i][j][0]), "v"(sc[i][j][1]));
      asm("v_cvt_pk_bf16_f32 %0, %1, %2"
          : "=v"(pf[i][1][j]) : "v"(sc[i][j][2]), "v"(sc[i][j][3]));
    }
  }
  __syncthreads();  // Vt staged & visible to all waves

  char* Pme = Pw + w * 6144;
  f32x4 o[3][4];
  #pragma unroll
  for (int i = 0; i < 3; i++)
    #pragma unroll
    for (int jd = 0; jd < 4; jd++) o[i][jd] = zero;
  #pragma unroll
  for (int kc = 0; kc < 3; kc++) {
    #pragma unroll
    for (int i = 0; i < 3; i++)
      #pragma unroll
      for (int rp = 0; rp < 2; rp++) {
        int row0 = i * 16 + lk4 * 4 + rp * 2;
        int row1 = row0 + 1;
        #pragma unroll
        for (int jj = 0; jj < 4; jj++) {
          unsigned int v = pf[i][rp][kc * 4 + jj];
          int c2 = (jj * 16 + lr) * 2;
          *(unsigned short*)(Pme + row0 * 128 + (c2 ^ ((row0 & 7) << 4))) = (unsigned short)v;
          *(unsigned short*)(Pme + row1 * 128 + (c2 ^ ((row1 & 7) << 4))) = (unsigned short)(v >> 16);
        }
      }
    asm volatile("s_waitcnt lgkmcnt(0)" ::: "memory");
    __builtin_amdgcn_sched_barrier(0);
    #pragma unroll
    for (int kk = 0; kk < 2; kk++) {
      short8 a[3], bb[4];
      #pragma unroll
      for (int i = 0; i < 3; i++) {
        int ra = i * 16 + lr;
        a[i] = *(const short8*)(Pme + ra * 128 + (((kk * 32 + lk4 * 8) * 2) ^ ((ra & 7) << 4)));
      }
      #pragma unroll
      for (int jd = 0; jd < 4; jd++) {
        int d = jd * 16 + lr;
        int byte = ((d * 400 + (kc * 64 + kk * 32 + lk4 * 8) * 2) ^ (((d >> 3) & 7) << 4));
        bb[jd] = *(const short8*)((const char*)Vt + byte);
      }
      __builtin_amdgcn_s_setprio(1);
      #pragma unroll
      for (int i = 0; i < 3; i++)
        #pragma unroll
        for (int jd = 0; jd < 4; jd++)
          o[i][jd] = __builtin_amdgcn_mfma_f32_16x16x32_bf16(a[i], bb[jd], o[i][jd], 0, 0, 0);
      __builtin_amdgcn_s_setprio(0);
    }
  }

  asm volatile("s_waitcnt lgkmcnt(0)" ::: "memory");
  __builtin_amdgcn_sched_barrier(0);
  #pragma unroll
  for (int i = 0; i < 3; i++)
    #pragma unroll
    for (int jd = 0; jd < 4; jd++)
      #pragma unroll
      for (int h2 = 0; h2 < 2; h2++) {
        unsigned int u;
        asm("v_cvt_pk_bf16_f32 %0, %1, %2"
            : "=v"(u) : "v"(o[i][jd][h2 * 2]), "v"(o[i][jd][h2 * 2 + 1]));
        int row0 = i * 16 + lk4 * 4 + h2 * 2;
        int row1 = row0 + 1;
        int c2 = (jd * 16 + lr) * 2;
        *(unsigned short*)(Pme + row0 * 128 + (c2 ^ ((row0 & 7) << 4))) = (unsigned short)u;
        *(unsigned short*)(Pme + row1 * 128 + (c2 ^ ((row1 & 7) << 4))) = (unsigned short)(u >> 16);
      }
  asm volatile("s_waitcnt lgkmcnt(0)" ::: "memory");
  __builtin_amdgcn_sched_barrier(0);
  unsigned short* ob2 = aout + (size_t)(bv * 192 + w * 48) * 512 + h * 64;
  #pragma unroll
  for (int p = 0; p < 6; p++) {
    int row = p * 8 + (l >> 3);
    int c = l & 7;
    int slot = (row & 7) << 4;
    short8 v = *(const short8*)(Pme + row * 128 + ((c * 16) ^ slot));
    *(short8*)(ob2 + (size_t)row * 512 + c * 8) = v;
  }
}

extern "C" void kernel_launch(void* const* d_in, const int* in_sizes, int n_in,
                              void* d_out, int out_size, void* d_ws, size_t ws_size,
                              hipStream_t stream) {
  const float* x     = (const float*)d_in[0];
  const int*   obs   = (const int*)d_in[1];
  const int*   pad   = (const int*)d_in[2];
  const float* gamma = (const float*)d_in[3];
  const float* beta  = (const float*)d_in[4];
  const float* Wq    = (const float*)d_in[5];
  const float* Wp    = (const float*)d_in[6];
  const float* bp    = (const float*)d_in[7];
  float* out = (float*)d_out;
  char* ws = (char*)d_ws;

  const size_t M = 49152;  // BV * T1 = 256 * 192
  unsigned short* xn  = (unsigned short*)ws;                             // M*512 bf16 (reused as attn out)
  unsigned short* qkv = (unsigned short*)(ws + M * 512 * 2);             // M*1536 bf16
  unsigned short* Wtq = (unsigned short*)(ws + M * 512 * 2 + M * 1536 * 2);
  unsigned short* Wtp = Wtq + 1536 * 512;

  ln_kernel<<<dim3(12800), dim3(256), 0, stream>>>(x, gamma, beta, xn, Wq, Wp, Wtq, Wtp);
  gemm_bt<0><<<dim3(12, 384), dim3(256), 0, stream>>>(
      xn, Wtq, qkv, nullptr, nullptr, nullptr, 49152, 1536, 512, 12);
  attn_kernel<<<dim3(8, 256), dim3(256), 0, stream>>>(qkv, xn, obs, pad);
  gemm_bt<1><<<dim3(4, 384), dim3(256), 0, stream>>>(
      xn, Wtp, nullptr, out, bp, x, 49152, 512, 512, 4);
}